// Round 3
// baseline (405.106 us; speedup 1.0000x reference)
//
#include <hip/hip_runtime.h>

// Problem constants (fixed by setup_inputs):
//   x: (16, 3, 1024, 1024) f32; control_points: (1, 2, 35, 35) f32
//   out = concat(transformed (16,3,1024,1024), deformation_field (2,1024,1024))
#define HW      1024
#define PLANE   (HW * HW)
#define NPLANES 48          // 16 * 3
#define CP      35
#define CPN     (CP * CP)
#define PPT     8           // planes per thread
#define ZCHUNKS (NPLANES / PPT)   // 6

typedef float f2v __attribute__((ext_vector_type(2)));

__global__ __launch_bounds__(256) void bspline_fused_kernel(
    const float* __restrict__ x,
    const float* __restrict__ cp,   // (2, 35, 35)
    float* __restrict__ out)
{
    const int j = blockIdx.x * blockDim.x + threadIdx.x;   // col
    const int i = blockIdx.y;                              // row
    const int pix = i * HW + j;

    // normalized grid coords (linspace(-1,1,1024))
    const float gx = (float)j * (2.0f / 1023.0f) - 1.0f;
    const float gy = (float)i * (2.0f / 1023.0f) - 1.0f;

    // ---- deformation field: bilinear sample of control points ----
    const float cpxc = gx * 17.0f + 17.0f;     // (cpx-1)/2 = 17
    const float cpyc = gy * 17.0f + 17.0f;
    float ix = (cpxc + 1.0f) * 0.5f * 34.0f;   // (W-1) = 34
    float iy = (cpyc + 1.0f) * 0.5f * 34.0f;
    ix = fminf(fmaxf(ix, 0.0f), 34.0f);
    iy = fminf(fmaxf(iy, 0.0f), 34.0f);
    const float ix0f = floorf(ix), iy0f = floorf(iy);
    const float wx = ix - ix0f,    wy = iy - iy0f;
    const int ix0 = (int)ix0f, iy0 = (int)iy0f;
    const int ix1 = min(ix0 + 1, 34), iy1 = min(iy0 + 1, 34);

    const int o00c = iy0 * CP + ix0, o01c = iy0 * CP + ix1;
    const int o10c = iy1 * CP + ix0, o11c = iy1 * CP + ix1;

    float df[2];
    #pragma unroll
    for (int c = 0; c < 2; ++c) {
        const float* cpc = cp + c * CPN;
        const float v00 = cpc[o00c], v01 = cpc[o01c];
        const float v10 = cpc[o10c], v11 = cpc[o11c];
        const float top = v00 * (1.0f - wx) + v01 * wx;
        const float bot = v10 * (1.0f - wx) + v11 * wx;
        df[c] = top * (1.0f - wy) + bot * wy;
    }

    // deformation_field output lives after the 48 transformed planes;
    // only the z==0 slice writes it (deterministic, identical every call)
    if (blockIdx.z == 0) {
        out[NPLANES * PLANE + 0 * PLANE + pix] = df[0];
        out[NPLANES * PLANE + 1 * PLANE + pix] = df[1];
    }

    // ---- image sampling coords (note df channel swap per reference) ----
    const float sxn = gx + df[1];
    const float syn = gy + df[0];
    float fx = (sxn + 1.0f) * 0.5f * 1023.0f;
    float fy = (syn + 1.0f) * 0.5f * 1023.0f;
    fx = fminf(fmaxf(fx, 0.0f), 1023.0f);
    fy = fminf(fmaxf(fy, 0.0f), 1023.0f);
    const float fx0f = floorf(fx), fy0f = floorf(fy);
    const float ux = fx - fx0f,    uy = fy - fy0f;
    const int X0 = (int)fx0f, Y0 = (int)fy0f;
    const int Y1 = min(Y0 + 1, 1023);

    // x-neighbor pair (b[o00], b[o00+1]) as ONE unaligned dwordx2.
    // Border fold: when X0==1023 (only possible when fx==1023.0 exactly,
    // where ux==0), shift the pair base down by one and move the clamp
    // into the x-weights:  top = t.x*wax + t.y*wbx
    //   interior: (wax,wbx) = (1-ux, ux)   pair = (v00, v01)
    //   border:   (wax,wbx) = (0, 1)       pair = (v00m1, v00) -> v00
    const int bshift = (X0 >= 1023) ? 1 : 0;
    const int a2t = Y0 * HW + X0 - bshift;   // row Y0 pair base
    const int a2b = Y1 * HW + X0 - bshift;   // row Y1 pair base
    const float wbx = bshift ? 1.0f : (fx - fx0f);
    const float wax = 1.0f - wbx;            // bshift ? 0 : (1-ux)
    const float omuy = 1.0f - uy;

    // ---- 8 planes per thread: 16 dwordx2 gathers (half the addresses
    // of 32 dword gathers; address-processing is the theorized limiter) ----
    const int p0 = blockIdx.z * PPT;
    const float* __restrict__ xp = x + (size_t)p0 * PLANE;
    float* __restrict__ op = out + (size_t)p0 * PLANE + pix;

    f2v t[PPT], bm[PPT];
    #pragma unroll
    for (int p = 0; p < PPT; ++p) {
        const float* b = xp + (size_t)p * PLANE;
        __builtin_memcpy(&t[p],  b + a2t, 8);   // align-4 8B load -> dwordx2
        __builtin_memcpy(&bm[p], b + a2b, 8);
    }
    __builtin_amdgcn_sched_barrier(0);   // loads stay clustered ahead of math
    #pragma unroll
    for (int p = 0; p < PPT; ++p) {
        const float top = t[p].x  * wax + t[p].y  * wbx;
        const float bot = bm[p].x * wax + bm[p].y * wbx;
        const float r   = top * omuy + bot * uy;
        __builtin_nontemporal_store(r, op + (size_t)p * PLANE);
    }
}

extern "C" void kernel_launch(void* const* d_in, const int* in_sizes, int n_in,
                              void* d_out, int out_size, void* d_ws, size_t ws_size,
                              hipStream_t stream) {
    const float* x  = (const float*)d_in[0];
    const float* cp = (const float*)d_in[1];
    float* out = (float*)d_out;

    dim3 block(256, 1, 1);
    dim3 grid(HW / 256, HW, ZCHUNKS);
    bspline_fused_kernel<<<grid, block, 0, stream>>>(x, cp, out);
}

// Round 4
// 398.227 us; speedup vs baseline: 1.0173x; 1.0173x over previous
//
#include <hip/hip_runtime.h>
#include <stdint.h>

// Problem constants (fixed by setup_inputs):
//   x: (16, 3, 1024, 1024) f32; control_points: (1, 2, 35, 35) f32
//   out = concat(transformed (16,3,1024,1024), deformation_field (2,1024,1024))
#define HW      1024
#define PLANE   (HW * HW)
#define NPLANES 48          // 16 * 3
#define CP      35
#define CPN     (CP * CP)
#define PPT     8           // planes per thread
#define ZCHUNKS (NPLANES / PPT)   // 6

typedef float f2v __attribute__((ext_vector_type(2)));

__global__ __launch_bounds__(256) void bspline_fused_kernel(
    const float* __restrict__ x,
    const float* __restrict__ cp,   // (2, 35, 35)
    float* __restrict__ out)
{
    const int j = blockIdx.x * blockDim.x + threadIdx.x;   // col
    const int i = blockIdx.y;                              // row
    const int pix = i * HW + j;

    // normalized grid coords (linspace(-1,1,1024))
    const float gx = (float)j * (2.0f / 1023.0f) - 1.0f;
    const float gy = (float)i * (2.0f / 1023.0f) - 1.0f;

    // ---- deformation field: bilinear sample of control points ----
    const float cpxc = gx * 17.0f + 17.0f;     // (cpx-1)/2 = 17
    const float cpyc = gy * 17.0f + 17.0f;
    float ix = (cpxc + 1.0f) * 0.5f * 34.0f;   // (W-1) = 34
    float iy = (cpyc + 1.0f) * 0.5f * 34.0f;
    ix = fminf(fmaxf(ix, 0.0f), 34.0f);
    iy = fminf(fmaxf(iy, 0.0f), 34.0f);
    const float ix0f = floorf(ix), iy0f = floorf(iy);
    const float wx = ix - ix0f,    wy = iy - iy0f;
    const int ix0 = (int)ix0f, iy0 = (int)iy0f;
    const int ix1 = min(ix0 + 1, 34), iy1 = min(iy0 + 1, 34);

    const int o00c = iy0 * CP + ix0, o01c = iy0 * CP + ix1;
    const int o10c = iy1 * CP + ix0, o11c = iy1 * CP + ix1;

    float df[2];
    #pragma unroll
    for (int c = 0; c < 2; ++c) {
        const float* cpc = cp + c * CPN;
        const float v00 = cpc[o00c], v01 = cpc[o01c];
        const float v10 = cpc[o10c], v11 = cpc[o11c];
        const float top = v00 * (1.0f - wx) + v01 * wx;
        const float bot = v10 * (1.0f - wx) + v11 * wx;
        df[c] = top * (1.0f - wy) + bot * wy;
    }

    // deformation_field output lives after the 48 transformed planes;
    // only the z==0 slice writes it (deterministic, identical every call)
    if (blockIdx.z == 0) {
        out[NPLANES * PLANE + 0 * PLANE + pix] = df[0];
        out[NPLANES * PLANE + 1 * PLANE + pix] = df[1];
    }

    // ---- image sampling coords (note df channel swap per reference) ----
    const float sxn = gx + df[1];
    const float syn = gy + df[0];
    float fx = (sxn + 1.0f) * 0.5f * 1023.0f;
    float fy = (syn + 1.0f) * 0.5f * 1023.0f;
    fx = fminf(fmaxf(fx, 0.0f), 1023.0f);
    fy = fminf(fmaxf(fy, 0.0f), 1023.0f);
    const float fx0f = floorf(fx), fy0f = floorf(fy);
    const float ux = fx - fx0f,    uy = fy - fy0f;
    const int X0 = (int)fx0f, Y0 = (int)fy0f;
    const int Y1 = min(Y0 + 1, 1023);

    // x-neighbor pair (b[o00], b[o00+1]) as ONE dwordx2 (4B-aligned; HW
    // handles the 8B-unaligned case). Border fold: X0==1023 only when
    // fx==1023.0 exactly (ux==0): shift pair base down 1, weights (0,1).
    const int bshift = (X0 >= 1023) ? 1 : 0;
    const uint32_t vot = (uint32_t)(Y0 * HW + X0 - bshift) * 4u;  // byte off, row Y0
    const uint32_t vob = (uint32_t)(Y1 * HW + X0 - bshift) * 4u;  // byte off, row Y1
    const float wbx = bshift ? 1.0f : (fx - fx0f);
    const float wax = 1.0f - wbx;
    const float omuy = 1.0f - uy;

    // ---- 8 planes per thread. The compiler has been re-serializing the
    // gather phase into per-plane batches (VGPR_Count 24-28 across three
    // source variants; wave lifetime ~21K cy = ~8 memory round-trips).
    // Force ALL 16 loads in flight with one asm block: 16 early-clobber
    // 64-bit dests + single vmcnt(0) at the end => one round-trip.
    // Plane bases are wave-uniform -> saddr form (SGPR pair + 32b voffset).
    const int p0 = blockIdx.z * PPT;
    const float* __restrict__ xp = x + (size_t)p0 * PLANE;
    float* __restrict__ op = out + (size_t)p0 * PLANE + pix;

    const float* b0 = xp + 0 * (size_t)PLANE;
    const float* b1 = xp + 1 * (size_t)PLANE;
    const float* b2 = xp + 2 * (size_t)PLANE;
    const float* b3 = xp + 3 * (size_t)PLANE;
    const float* b4 = xp + 4 * (size_t)PLANE;
    const float* b5 = xp + 5 * (size_t)PLANE;
    const float* b6 = xp + 6 * (size_t)PLANE;
    const float* b7 = xp + 7 * (size_t)PLANE;

    f2v t0, t1, t2, t3, t4, t5, t6, t7;   // row Y0 pairs
    f2v m0, m1, m2, m3, m4, m5, m6, m7;   // row Y1 pairs
    asm volatile(
        "global_load_dwordx2 %[t0], %[ot], %[p0]\n\t"
        "global_load_dwordx2 %[m0], %[ob], %[p0]\n\t"
        "global_load_dwordx2 %[t1], %[ot], %[p1]\n\t"
        "global_load_dwordx2 %[m1], %[ob], %[p1]\n\t"
        "global_load_dwordx2 %[t2], %[ot], %[p2]\n\t"
        "global_load_dwordx2 %[m2], %[ob], %[p2]\n\t"
        "global_load_dwordx2 %[t3], %[ot], %[p3]\n\t"
        "global_load_dwordx2 %[m3], %[ob], %[p3]\n\t"
        "global_load_dwordx2 %[t4], %[ot], %[p4]\n\t"
        "global_load_dwordx2 %[m4], %[ob], %[p4]\n\t"
        "global_load_dwordx2 %[t5], %[ot], %[p5]\n\t"
        "global_load_dwordx2 %[m5], %[ob], %[p5]\n\t"
        "global_load_dwordx2 %[t6], %[ot], %[p6]\n\t"
        "global_load_dwordx2 %[m6], %[ob], %[p6]\n\t"
        "global_load_dwordx2 %[t7], %[ot], %[p7]\n\t"
        "global_load_dwordx2 %[m7], %[ob], %[p7]\n\t"
        "s_waitcnt vmcnt(0)"
        : [t0]"=&v"(t0), [m0]"=&v"(m0), [t1]"=&v"(t1), [m1]"=&v"(m1),
          [t2]"=&v"(t2), [m2]"=&v"(m2), [t3]"=&v"(t3), [m3]"=&v"(m3),
          [t4]"=&v"(t4), [m4]"=&v"(m4), [t5]"=&v"(t5), [m5]"=&v"(m5),
          [t6]"=&v"(t6), [m6]"=&v"(m6), [t7]"=&v"(t7), [m7]"=&v"(m7)
        : [ot]"v"(vot), [ob]"v"(vob),
          [p0]"s"(b0), [p1]"s"(b1), [p2]"s"(b2), [p3]"s"(b3),
          [p4]"s"(b4), [p5]"s"(b5), [p6]"s"(b6), [p7]"s"(b7)
        : "memory");

    f2v t[PPT] = {t0, t1, t2, t3, t4, t5, t6, t7};
    f2v m[PPT] = {m0, m1, m2, m3, m4, m5, m6, m7};
    #pragma unroll
    for (int p = 0; p < PPT; ++p) {
        const float top = t[p].x * wax + t[p].y * wbx;
        const float bot = m[p].x * wax + m[p].y * wbx;
        const float r   = top * omuy + bot * uy;
        __builtin_nontemporal_store(r, op + (size_t)p * PLANE);
    }
}

extern "C" void kernel_launch(void* const* d_in, const int* in_sizes, int n_in,
                              void* d_out, int out_size, void* d_ws, size_t ws_size,
                              hipStream_t stream) {
    const float* x  = (const float*)d_in[0];
    const float* cp = (const float*)d_in[1];
    float* out = (float*)d_out;

    dim3 block(256, 1, 1);
    dim3 grid(HW / 256, HW, ZCHUNKS);
    bspline_fused_kernel<<<grid, block, 0, stream>>>(x, cp, out);
}